// Round 7
// baseline (212.466 us; speedup 1.0000x reference)
//
#include <hip/hip_runtime.h>
#include <math.h>

// Problem constants (fixed by the reference setup_inputs()).
#define G_NUM   2048
#define N_PTS   65536
#define K_FREQ  8
#define REC     64            // floats per record: every scalar DUPLICATED {v,v}
#define CHUNKS  32            // gaussian list split across gridDim.y
#define G_PER_CHUNK (G_NUM / CHUNKS)                              // 64
#define PACK_BYTES ((size_t)G_NUM * REC * sizeof(float))          // 512 KiB
#define PART_FLOATS ((size_t)N_PTS * 3)                           // per chunk
#define PART_BYTES  (PART_FLOATS * sizeof(float) * CHUNKS)        // ~25.2 MB

typedef float v2f __attribute__((ext_vector_type(2)));

// HW trans: v_cos_f32 takes revolutions (cos(2*pi*p)), valid to |p|<=256;
// here |p| <= 127*sqrt(2) ~ 180. Both are quarter-rate (8 cyc/wave64) and
// block VALU issue — measured R6: busy = sum of fma+trans pipes.
#if __has_builtin(__builtin_amdgcn_cosf)
__device__ __forceinline__ float hw_cos_rev(float p) { return __builtin_amdgcn_cosf(p); }
#else
__device__ __forceinline__ float hw_cos_rev(float p) { return __cosf(6.28318530717958648f * p); }
#endif
#if __has_builtin(__builtin_amdgcn_exp2f)
__device__ __forceinline__ float hw_exp2(float p) { return __builtin_amdgcn_exp2f(p); }
#else
__device__ __forceinline__ float hw_exp2(float p) { return exp2f(p); }
#endif

// v_pk_fma_f32: measured 4 cyc/wave64 (no rate gain over scalar — only
// instruction-count/fetch benefit). Keep packed to halve op count.
__device__ __forceinline__ v2f fma2v(v2f a, v2f b, v2f c) {
#if __has_builtin(__builtin_elementwise_fma)
    return __builtin_elementwise_fma(a, b, c);
#else
    v2f r; r.x = fmaf(a.x, b.x, c.x); r.y = fmaf(a.y, b.y, c.y); return r;
#endif
}

// Record layout in duplicated v2f pairs ({v,v}, even dword offset):
// [0]=tx [1]=ty [2]=cth [3]=sth [4]=-sth [5]=A [6]=B [7..9]=rgb
// [10..17]=freq_k [18..25]=coef_k [26..31]=pad
// tx = -(c*px + s*py), ty = s*px - c*py,
// A = -0.5*log2(e)*sx^2, B = -0.5*log2(e)*sy^2.
// rx = c*xi + s*yi + tx ; ry = c*yi - s*xi + ty ; env = exp2(A*rx^2 + B*ry^2)
__global__ __launch_bounds__(256) void pack_kernel(
    const float* __restrict__ colors, const float* __restrict__ pos,
    const float* __restrict__ scales, const float* __restrict__ rot,
    const float* __restrict__ coef,   const int* __restrict__ idx,
    float* __restrict__ pack)
{
    int j = blockIdx.x * blockDim.x + threadIdx.x;
    if (j >= G_NUM) return;
    float th = rot[j];
    float c = cosf(th), s = sinf(th);
    float px = pos[2 * j], py = pos[2 * j + 1];
    float sx = scales[2 * j], sy = scales[2 * j + 1];
    const float nhl2e = -0.72134752044448170368f;  // -0.5 * log2(e)
    float* r = pack + (size_t)j * REC;
    auto put = [&](int pair, float v) { r[2 * pair] = v; r[2 * pair + 1] = v; };
    put(0, -(c * px + s * py));
    put(1, s * px - c * py);
    put(2, c);
    put(3, s);
    put(4, -s);
    put(5, nhl2e * sx * sx);
    put(6, nhl2e * sy * sy);
    put(7, colors[3 * j]);
    put(8, colors[3 * j + 1]);
    put(9, colors[3 * j + 2]);
#pragma unroll
    for (int k = 0; k < K_FREQ; ++k) {
        // freq = idx * (MAX_FREQ/NUM_TOTAL_FREQ) = idx * 1.0 (revs per rx)
        put(10 + k, (float)idx[j * K_FREQ + k]);
        put(18 + k, coef[j * K_FREQ + k]);
    }
#pragma unroll
    for (int p = 26; p < 32; ++p) put(p, 0.0f);
}

// 4 points/thread (two packed pairs), 8 waves/SIMD. Per-gaussian params via
// wave-uniform s_load from duplicated-pair records. unroll 2 so the compiler
// software-pipelines next-iteration s_loads past the current body (the ~20%
// no-issue stall of R6 was record-fetch latency under unroll 1).
template <bool USE_PART>
__global__ __launch_bounds__(256, 8) void periodic2d_kernel(
    const float* __restrict__ x, const float* __restrict__ pack,
    float* __restrict__ dst /* part buffer or out */)
{
    const int t = blockIdx.x * 256 + threadIdx.x;   // 0 .. N/4-1
    const int p0 = t;
    const int p1 = t + N_PTS / 4;
    const int p2 = t + N_PTS / 2;
    const int p3 = t + 3 * (N_PTS / 4);
    const float2 q0 = ((const float2*)x)[p0];
    const float2 q1 = ((const float2*)x)[p1];
    const float2 q2 = ((const float2*)x)[p2];
    const float2 q3 = ((const float2*)x)[p3];
    const v2f xiA = {q0.x, q1.x}, yiA = {q0.y, q1.y};
    const v2f xiB = {q2.x, q3.x}, yiB = {q2.y, q3.y};
    v2f a0A = {0.f, 0.f}, a1A = {0.f, 0.f}, a2A = {0.f, 0.f};
    v2f a0B = {0.f, 0.f}, a1B = {0.f, 0.f}, a2B = {0.f, 0.f};

    const v2f* __restrict__ rv =
        (const v2f*)(pack + (size_t)(blockIdx.y * G_PER_CHUNK) * REC);
#pragma unroll 2
    for (int j = 0; j < G_PER_CHUNK; ++j, rv += REC / 2) {
        // rx = c*xi + s*yi + tx ; ry = c*yi + (-s)*xi + ty   (2 fma each)
        const v2f rxA = fma2v(xiA, rv[2], fma2v(yiA, rv[3], rv[0]));
        const v2f rxB = fma2v(xiB, rv[2], fma2v(yiB, rv[3], rv[0]));
        const v2f ryA = fma2v(yiA, rv[2], fma2v(xiA, rv[4], rv[1]));
        const v2f ryB = fma2v(yiB, rv[2], fma2v(xiB, rv[4], rv[1]));
        const v2f eargA = fma2v(ryA * rv[6], ryA, (rxA * rv[5]) * rxA);
        const v2f eargB = fma2v(ryB * rv[6], ryB, (rxB * rv[5]) * rxB);
        v2f envA, envB;
        envA.x = hw_exp2(eargA.x); envA.y = hw_exp2(eargA.y);
        envB.x = hw_exp2(eargB.x); envB.y = hw_exp2(eargB.y);
        v2f waveA = {0.f, 0.f}, waveB = {0.f, 0.f};
#pragma unroll
        for (int k = 0; k < K_FREQ; ++k) {
            const v2f phA = rxA * rv[10 + k];
            const v2f phB = rxB * rv[10 + k];
            v2f cA, cB;
            cA.x = hw_cos_rev(phA.x); cA.y = hw_cos_rev(phA.y);
            cB.x = hw_cos_rev(phB.x); cB.y = hw_cos_rev(phB.y);
            waveA = fma2v(cA, rv[18 + k], waveA);
            waveB = fma2v(cB, rv[18 + k], waveB);
        }
        const v2f wA = envA * waveA;
        const v2f wB = envB * waveB;
        a0A = fma2v(wA, rv[7], a0A);  a0B = fma2v(wB, rv[7], a0B);
        a1A = fma2v(wA, rv[8], a1A);  a1B = fma2v(wB, rv[8], a1B);
        a2A = fma2v(wA, rv[9], a2A);  a2B = fma2v(wB, rv[9], a2B);
    }

    if (USE_PART) {
        float* o = dst + (size_t)blockIdx.y * PART_FLOATS;
        o[3 * p0 + 0] = a0A.x; o[3 * p0 + 1] = a1A.x; o[3 * p0 + 2] = a2A.x;
        o[3 * p1 + 0] = a0A.y; o[3 * p1 + 1] = a1A.y; o[3 * p1 + 2] = a2A.y;
        o[3 * p2 + 0] = a0B.x; o[3 * p2 + 1] = a1B.x; o[3 * p2 + 2] = a2B.x;
        o[3 * p3 + 0] = a0B.y; o[3 * p3 + 1] = a1B.y; o[3 * p3 + 2] = a2B.y;
    } else {
        atomicAdd(&dst[3 * p0 + 0], a0A.x);
        atomicAdd(&dst[3 * p0 + 1], a1A.x);
        atomicAdd(&dst[3 * p0 + 2], a2A.x);
        atomicAdd(&dst[3 * p1 + 0], a0A.y);
        atomicAdd(&dst[3 * p1 + 1], a1A.y);
        atomicAdd(&dst[3 * p1 + 2], a2A.y);
        atomicAdd(&dst[3 * p2 + 0], a0B.x);
        atomicAdd(&dst[3 * p2 + 1], a1B.x);
        atomicAdd(&dst[3 * p2 + 2], a2B.x);
        atomicAdd(&dst[3 * p3 + 0], a0B.y);
        atomicAdd(&dst[3 * p3 + 1], a1B.y);
        atomicAdd(&dst[3 * p3 + 2], a2B.y);
    }
}

// Sum the CHUNKS partial slices; float4 per thread.
__global__ __launch_bounds__(256) void reduce_kernel(
    const float* __restrict__ part, float* __restrict__ out)
{
    const int i = blockIdx.x * 256 + threadIdx.x;   // < N_PTS*3/4
    float4 s = {0.f, 0.f, 0.f, 0.f};
#pragma unroll
    for (int c = 0; c < CHUNKS; ++c) {
        const float4 v = ((const float4*)(part + (size_t)c * PART_FLOATS))[i];
        s.x += v.x; s.y += v.y; s.z += v.z; s.w += v.w;
    }
    ((float4*)out)[i] = s;
}

extern "C" void kernel_launch(void* const* d_in, const int* in_sizes, int n_in,
                              void* d_out, int out_size, void* d_ws, size_t ws_size,
                              hipStream_t stream)
{
    const float* x      = (const float*)d_in[0];
    const float* colors = (const float*)d_in[1];
    const float* pos    = (const float*)d_in[2];
    const float* scales = (const float*)d_in[3];
    const float* rot    = (const float*)d_in[4];
    const float* coef   = (const float*)d_in[5];
    const int*   idx    = (const int*)d_in[6];
    float* out  = (float*)d_out;
    float* pack = (float*)d_ws;
    float* part = (float*)((char*)d_ws + PACK_BYTES);

    pack_kernel<<<dim3((G_NUM + 255) / 256), 256, 0, stream>>>(
        colors, pos, scales, rot, coef, idx, pack);

    if (ws_size >= PACK_BYTES + PART_BYTES) {
        periodic2d_kernel<true><<<dim3(N_PTS / 1024, CHUNKS), 256, 0, stream>>>(
            x, pack, part);
        reduce_kernel<<<dim3((N_PTS * 3 / 4) / 256), 256, 0, stream>>>(part, out);
    } else {
        (void)hipMemsetAsync(d_out, 0, (size_t)out_size * sizeof(float), stream);
        periodic2d_kernel<false><<<dim3(N_PTS / 1024, CHUNKS), 256, 0, stream>>>(
            x, pack, out);
    }
}

// Round 8
// 202.182 us; speedup vs baseline: 1.0509x; 1.0509x over previous
//
#include <hip/hip_runtime.h>
#include <math.h>

// Problem constants (fixed by the reference setup_inputs()).
#define G_NUM   2048
#define N_PTS   65536
#define K_FREQ  8
#define REC     64            // floats per record: every scalar DUPLICATED {v,v}
#define CHUNKS  32            // gaussian list split across gridDim.y
#define G_PER_CHUNK (G_NUM / CHUNKS)                              // 64
#define PACK_BYTES ((size_t)G_NUM * REC * sizeof(float))          // 512 KiB
#define PART_FLOATS ((size_t)N_PTS * 3)                           // per chunk
#define PART_BYTES  (PART_FLOATS * sizeof(float) * CHUNKS)        // ~25.2 MB
#define LDS_FLOATS  (G_PER_CHUNK * REC)                           // 4096 (16 KB)

typedef float v2f __attribute__((ext_vector_type(2)));

// HW trans: v_cos_f32 takes revolutions (cos(2*pi*p)), valid to |p|<=256;
// here |p| <= 127*sqrt(2) ~ 180. Trans = 8 cyc/wave64 and blocks VALU issue
// (measured R6: busy = sum of fma+trans pipes, no overlap).
#if __has_builtin(__builtin_amdgcn_cosf)
__device__ __forceinline__ float hw_cos_rev(float p) { return __builtin_amdgcn_cosf(p); }
#else
__device__ __forceinline__ float hw_cos_rev(float p) { return __cosf(6.28318530717958648f * p); }
#endif
#if __has_builtin(__builtin_amdgcn_exp2f)
__device__ __forceinline__ float hw_exp2(float p) { return __builtin_amdgcn_exp2f(p); }
#else
__device__ __forceinline__ float hw_exp2(float p) { return exp2f(p); }
#endif

// v_pk_fma_f32: 4 cyc/wave64 (no rate gain over scalar f32 — halves
// instruction count only). Operands here come from LDS-loaded VGPR pairs,
// so there is no SGPR-per-instruction constraint and no mov materialization.
__device__ __forceinline__ v2f fma2v(v2f a, v2f b, v2f c) {
#if __has_builtin(__builtin_elementwise_fma)
    return __builtin_elementwise_fma(a, b, c);
#else
    v2f r; r.x = fmaf(a.x, b.x, c.x); r.y = fmaf(a.y, b.y, c.y); return r;
#endif
}

// Record layout in duplicated v2f pairs ({v,v}, even dword offset):
// [0]=tx [1]=ty [2]=cth [3]=sth [4]=-sth [5]=A [6]=B [7..9]=rgb
// [10..17]=freq_k [18..25]=coef_k [26..31]=pad
// tx = -(c*px + s*py), ty = s*px - c*py,
// A = -0.5*log2(e)*sx^2, B = -0.5*log2(e)*sy^2.
// rx = c*xi + s*yi + tx ; ry = c*yi - s*xi + ty ; env = exp2(A*rx^2 + B*ry^2)
__global__ __launch_bounds__(256) void pack_kernel(
    const float* __restrict__ colors, const float* __restrict__ pos,
    const float* __restrict__ scales, const float* __restrict__ rot,
    const float* __restrict__ coef,   const int* __restrict__ idx,
    float* __restrict__ pack)
{
    int j = blockIdx.x * blockDim.x + threadIdx.x;
    if (j >= G_NUM) return;
    float th = rot[j];
    float c = cosf(th), s = sinf(th);
    float px = pos[2 * j], py = pos[2 * j + 1];
    float sx = scales[2 * j], sy = scales[2 * j + 1];
    const float nhl2e = -0.72134752044448170368f;  // -0.5 * log2(e)
    float* r = pack + (size_t)j * REC;
    auto put = [&](int pair, float v) { r[2 * pair] = v; r[2 * pair + 1] = v; };
    put(0, -(c * px + s * py));
    put(1, s * px - c * py);
    put(2, c);
    put(3, s);
    put(4, -s);
    put(5, nhl2e * sx * sx);
    put(6, nhl2e * sy * sy);
    put(7, colors[3 * j]);
    put(8, colors[3 * j + 1]);
    put(9, colors[3 * j + 2]);
#pragma unroll
    for (int k = 0; k < K_FREQ; ++k) {
        // freq = idx * (MAX_FREQ/NUM_TOTAL_FREQ) = idx * 1.0 (revs per rx)
        put(10 + k, (float)idx[j * K_FREQ + k]);
        put(18 + k, coef[j * K_FREQ + k]);
    }
#pragma unroll
    for (int p = 26; p < 32; ++p) put(p, 0.0f);
}

// 4 points/thread (two packed pairs), 8 waves/SIMD. Records are staged to
// LDS once per block (16 KB); the K-loop reads them with WAVE-UNIFORM
// ds_read (broadcast: conflict-free, ~1 clk LDS pipe each, deep lgkmcnt
// pipelining). This removes the per-iteration s_load->waitcnt serialization
// that SGPR pressure (52 live dwords/record vs ~80 SGPRs) made unavoidable
// in the SMEM path (R6/R7).
template <bool USE_PART>
__global__ __launch_bounds__(256, 8) void periodic2d_kernel(
    const float* __restrict__ x, const float* __restrict__ pack,
    float* __restrict__ dst /* part buffer or out */)
{
    __shared__ float lds_rec[LDS_FLOATS];

    // Cooperative stage: 4096 floats = 1024 float4, 256 threads x 4.
    {
        const float4* __restrict__ src = (const float4*)
            (pack + (size_t)(blockIdx.y * G_PER_CHUNK) * REC);
        float4* dstl = (float4*)lds_rec;
#pragma unroll
        for (int i = 0; i < LDS_FLOATS / 4 / 256; ++i)
            dstl[threadIdx.x + 256 * i] = src[threadIdx.x + 256 * i];
    }
    __syncthreads();

    const int t = blockIdx.x * 256 + threadIdx.x;   // 0 .. N/4-1
    const int p0 = t;
    const int p1 = t + N_PTS / 4;
    const int p2 = t + N_PTS / 2;
    const int p3 = t + 3 * (N_PTS / 4);
    const float2 q0 = ((const float2*)x)[p0];
    const float2 q1 = ((const float2*)x)[p1];
    const float2 q2 = ((const float2*)x)[p2];
    const float2 q3 = ((const float2*)x)[p3];
    const v2f xiA = {q0.x, q1.x}, yiA = {q0.y, q1.y};
    const v2f xiB = {q2.x, q3.x}, yiB = {q2.y, q3.y};
    v2f a0A = {0.f, 0.f}, a1A = {0.f, 0.f}, a2A = {0.f, 0.f};
    v2f a0B = {0.f, 0.f}, a1B = {0.f, 0.f}, a2B = {0.f, 0.f};

    const v2f* rv = (const v2f*)lds_rec;
#pragma unroll 1
    for (int j = 0; j < G_PER_CHUNK; ++j, rv += REC / 2) {
        // rx = c*xi + s*yi + tx ; ry = c*yi + (-s)*xi + ty   (2 fma each)
        const v2f rxA = fma2v(xiA, rv[2], fma2v(yiA, rv[3], rv[0]));
        const v2f rxB = fma2v(xiB, rv[2], fma2v(yiB, rv[3], rv[0]));
        const v2f ryA = fma2v(yiA, rv[2], fma2v(xiA, rv[4], rv[1]));
        const v2f ryB = fma2v(yiB, rv[2], fma2v(xiB, rv[4], rv[1]));
        const v2f eargA = fma2v(ryA * rv[6], ryA, (rxA * rv[5]) * rxA);
        const v2f eargB = fma2v(ryB * rv[6], ryB, (rxB * rv[5]) * rxB);
        v2f envA, envB;
        envA.x = hw_exp2(eargA.x); envA.y = hw_exp2(eargA.y);
        envB.x = hw_exp2(eargB.x); envB.y = hw_exp2(eargB.y);
        v2f waveA = {0.f, 0.f}, waveB = {0.f, 0.f};
#pragma unroll
        for (int k = 0; k < K_FREQ; ++k) {
            const v2f phA = rxA * rv[10 + k];
            const v2f phB = rxB * rv[10 + k];
            v2f cA, cB;
            cA.x = hw_cos_rev(phA.x); cA.y = hw_cos_rev(phA.y);
            cB.x = hw_cos_rev(phB.x); cB.y = hw_cos_rev(phB.y);
            waveA = fma2v(cA, rv[18 + k], waveA);
            waveB = fma2v(cB, rv[18 + k], waveB);
        }
        const v2f wA = envA * waveA;
        const v2f wB = envB * waveB;
        a0A = fma2v(wA, rv[7], a0A);  a0B = fma2v(wB, rv[7], a0B);
        a1A = fma2v(wA, rv[8], a1A);  a1B = fma2v(wB, rv[8], a1B);
        a2A = fma2v(wA, rv[9], a2A);  a2B = fma2v(wB, rv[9], a2B);
    }

    if (USE_PART) {
        float* o = dst + (size_t)blockIdx.y * PART_FLOATS;
        o[3 * p0 + 0] = a0A.x; o[3 * p0 + 1] = a1A.x; o[3 * p0 + 2] = a2A.x;
        o[3 * p1 + 0] = a0A.y; o[3 * p1 + 1] = a1A.y; o[3 * p1 + 2] = a2A.y;
        o[3 * p2 + 0] = a0B.x; o[3 * p2 + 1] = a1B.x; o[3 * p2 + 2] = a2B.x;
        o[3 * p3 + 0] = a0B.y; o[3 * p3 + 1] = a1B.y; o[3 * p3 + 2] = a2B.y;
    } else {
        atomicAdd(&dst[3 * p0 + 0], a0A.x);
        atomicAdd(&dst[3 * p0 + 1], a1A.x);
        atomicAdd(&dst[3 * p0 + 2], a2A.x);
        atomicAdd(&dst[3 * p1 + 0], a0A.y);
        atomicAdd(&dst[3 * p1 + 1], a1A.y);
        atomicAdd(&dst[3 * p1 + 2], a2A.y);
        atomicAdd(&dst[3 * p2 + 0], a0B.x);
        atomicAdd(&dst[3 * p2 + 1], a1B.x);
        atomicAdd(&dst[3 * p2 + 2], a2B.x);
        atomicAdd(&dst[3 * p3 + 0], a0B.y);
        atomicAdd(&dst[3 * p3 + 1], a1B.y);
        atomicAdd(&dst[3 * p3 + 2], a2B.y);
    }
}

// Sum the CHUNKS partial slices; float4 per thread.
__global__ __launch_bounds__(256) void reduce_kernel(
    const float* __restrict__ part, float* __restrict__ out)
{
    const int i = blockIdx.x * 256 + threadIdx.x;   // < N_PTS*3/4
    float4 s = {0.f, 0.f, 0.f, 0.f};
#pragma unroll
    for (int c = 0; c < CHUNKS; ++c) {
        const float4 v = ((const float4*)(part + (size_t)c * PART_FLOATS))[i];
        s.x += v.x; s.y += v.y; s.z += v.z; s.w += v.w;
    }
    ((float4*)out)[i] = s;
}

extern "C" void kernel_launch(void* const* d_in, const int* in_sizes, int n_in,
                              void* d_out, int out_size, void* d_ws, size_t ws_size,
                              hipStream_t stream)
{
    const float* x      = (const float*)d_in[0];
    const float* colors = (const float*)d_in[1];
    const float* pos    = (const float*)d_in[2];
    const float* scales = (const float*)d_in[3];
    const float* rot    = (const float*)d_in[4];
    const float* coef   = (const float*)d_in[5];
    const int*   idx    = (const int*)d_in[6];
    float* out  = (float*)d_out;
    float* pack = (float*)d_ws;
    float* part = (float*)((char*)d_ws + PACK_BYTES);

    pack_kernel<<<dim3((G_NUM + 255) / 256), 256, 0, stream>>>(
        colors, pos, scales, rot, coef, idx, pack);

    if (ws_size >= PACK_BYTES + PART_BYTES) {
        periodic2d_kernel<true><<<dim3(N_PTS / 1024, CHUNKS), 256, 0, stream>>>(
            x, pack, part);
        reduce_kernel<<<dim3((N_PTS * 3 / 4) / 256), 256, 0, stream>>>(part, out);
    } else {
        (void)hipMemsetAsync(d_out, 0, (size_t)out_size * sizeof(float), stream);
        periodic2d_kernel<false><<<dim3(N_PTS / 1024, CHUNKS), 256, 0, stream>>>(
            x, pack, out);
    }
}